// Round 1
// baseline (702.574 us; speedup 1.0000x reference)
//
#include <hip/hip_runtime.h>
#include <hip/hip_bf16.h>
#include <math.h>

// Problem constants (from reference setup_inputs)
//   N=10000, E=320000, in_dim=256, heads=4, hidden=64 (C1=256), out=40
#define IN_DIM 256
#define C1 256      // heads*hidden
#define H1 4
#define D1 64
#define OUT_DIM 40
#define NEG_SLOPE 0.2f

__device__ __forceinline__ void atomicMaxFloat(float* addr, float val) {
    if (val >= 0.0f) {
        atomicMax((int*)addr, __float_as_int(val));
    } else {
        atomicMin((unsigned int*)addr, __float_as_uint(val));
    }
}

// ---------------- init ----------------
__global__ void k_init(float* m1, float* s1, float* agg1,
                       float* m2, float* s2, float* agg2, int N) {
    int i = blockIdx.x * blockDim.x + threadIdx.x;
    int tot = N * C1;
    if (i < tot) agg1[i] = 0.0f;
    if (i < N * H1) { m1[i] = -INFINITY; s1[i] = 0.0f; }
    if (i < N)      { m2[i] = -INFINITY; s2[i] = 0.0f; }
    if (i < N * OUT_DIM) agg2[i] = 0.0f;
}

// ---------------- layer 1 GEMM + attention dots ----------------
// block = 256 threads (one node row), grid = N
__global__ void k_gemm1(const float* __restrict__ x, const float* __restrict__ W1,
                        const float* __restrict__ a_src, const float* __restrict__ a_dst,
                        float* __restrict__ h1, float* __restrict__ as1, float* __restrict__ ad1) {
    int n = blockIdx.x;
    int t = threadIdx.x;
    __shared__ float xs[IN_DIM];
    xs[t] = x[n * IN_DIM + t];
    __syncthreads();
    float acc = 0.0f;
#pragma unroll 8
    for (int k = 0; k < IN_DIM; ++k) {
        acc += xs[k] * W1[k * C1 + t];
    }
    h1[n * C1 + t] = acc;
    // attention dot products: att_src1/att_dst1 are [H1, D1] flattened == t
    float ps = acc * a_src[t];
    float pd = acc * a_dst[t];
    // wave (64-lane) reduction; wave w == head w
#pragma unroll
    for (int o = 32; o > 0; o >>= 1) {
        ps += __shfl_down(ps, o);
        pd += __shfl_down(pd, o);
    }
    int head = t >> 6;
    if ((t & 63) == 0) {
        as1[n * H1 + head] = ps;
        ad1[n * H1 + head] = pd;
    }
}

// ---------------- layer 1 edge kernels ----------------
__global__ void k_edge_max1(const int* __restrict__ ei, int E, int ET,
                            const float* __restrict__ as1, const float* __restrict__ ad1,
                            float* __restrict__ e1, float* __restrict__ m1) {
    int e = blockIdx.x * blockDim.x + threadIdx.x;
    if (e >= ET) return;
    int s, d;
    if (e < E) { s = ei[e]; d = ei[E + e]; }
    else { s = e - E; d = s; }
#pragma unroll
    for (int h = 0; h < H1; ++h) {
        float v = as1[s * H1 + h] + ad1[d * H1 + h];
        v = (v >= 0.0f) ? v : NEG_SLOPE * v;
        e1[e * H1 + h] = v;
        atomicMaxFloat(&m1[d * H1 + h], v);
    }
}

__global__ void k_edge_exp1(const int* __restrict__ ei, int E, int ET,
                            float* __restrict__ e1, const float* __restrict__ m1,
                            float* __restrict__ s1) {
    int e = blockIdx.x * blockDim.x + threadIdx.x;
    if (e >= ET) return;
    int d;
    if (e < E) { d = ei[E + e]; }
    else { d = e - E; }
#pragma unroll
    for (int h = 0; h < H1; ++h) {
        float ex = expf(e1[e * H1 + h] - m1[d * H1 + h]);
        e1[e * H1 + h] = ex;
        atomicAdd(&s1[d * H1 + h], ex);
    }
}

// one block (256 threads) per edge: t = head*64 + dd
__global__ void k_agg1(const int* __restrict__ ei, int E, int ET,
                       const float* __restrict__ e1, const float* __restrict__ s1,
                       const float* __restrict__ h1, float* __restrict__ agg1) {
    int e = blockIdx.x;
    if (e >= ET) return;
    int t = threadIdx.x;
    int s, d;
    if (e < E) { s = ei[e]; d = ei[E + e]; }
    else { s = e - E; d = s; }
    int h = t >> 6;
    float alpha = e1[e * H1 + h] / s1[d * H1 + h];
    float val = h1[s * C1 + t] * alpha;
    atomicAdd(&agg1[d * C1 + t], val);
}

// ---------------- layer 2 GEMM (+relu+bias on input) + attention dots ----------------
// block = 64 threads, grid = N
__global__ void k_gemm2(const float* __restrict__ agg1, const float* __restrict__ bias1,
                        const float* __restrict__ W2,
                        const float* __restrict__ a_src, const float* __restrict__ a_dst,
                        float* __restrict__ h2, float* __restrict__ as2, float* __restrict__ ad2) {
    int n = blockIdx.x;
    int t = threadIdx.x;  // 64
    __shared__ float xs[C1];
    for (int i = t; i < C1; i += 64) {
        float v = agg1[n * C1 + i] + bias1[i];
        xs[i] = (v > 0.0f) ? v : 0.0f;
    }
    __syncthreads();
    float acc = 0.0f;
    if (t < OUT_DIM) {
#pragma unroll 8
        for (int k = 0; k < C1; ++k) {
            acc += xs[k] * W2[k * OUT_DIM + t];
        }
        h2[n * OUT_DIM + t] = acc;
    }
    float ps = (t < OUT_DIM) ? acc * a_src[t] : 0.0f;
    float pd = (t < OUT_DIM) ? acc * a_dst[t] : 0.0f;
#pragma unroll
    for (int o = 32; o > 0; o >>= 1) {
        ps += __shfl_down(ps, o);
        pd += __shfl_down(pd, o);
    }
    if (t == 0) { as2[n] = ps; ad2[n] = pd; }
}

// ---------------- layer 2 edge kernels (H=1) ----------------
__global__ void k_edge_max2(const int* __restrict__ ei, int E, int ET,
                            const float* __restrict__ as2, const float* __restrict__ ad2,
                            float* __restrict__ e2, float* __restrict__ m2) {
    int e = blockIdx.x * blockDim.x + threadIdx.x;
    if (e >= ET) return;
    int s, d;
    if (e < E) { s = ei[e]; d = ei[E + e]; }
    else { s = e - E; d = s; }
    float v = as2[s] + ad2[d];
    v = (v >= 0.0f) ? v : NEG_SLOPE * v;
    e2[e] = v;
    atomicMaxFloat(&m2[d], v);
}

__global__ void k_edge_exp2(const int* __restrict__ ei, int E, int ET,
                            float* __restrict__ e2, const float* __restrict__ m2,
                            float* __restrict__ s2) {
    int e = blockIdx.x * blockDim.x + threadIdx.x;
    if (e >= ET) return;
    int d;
    if (e < E) { d = ei[E + e]; }
    else { d = e - E; }
    float ex = expf(e2[e] - m2[d]);
    e2[e] = ex;
    atomicAdd(&s2[d], ex);
}

// block = 320 threads = 8 edges x 40 lanes
__global__ void k_agg2(const int* __restrict__ ei, int E, int ET,
                       const float* __restrict__ e2, const float* __restrict__ s2,
                       const float* __restrict__ h2, float* __restrict__ agg2) {
    int t = threadIdx.x;
    int sub = t / OUT_DIM;
    int j = t % OUT_DIM;
    int e = blockIdx.x * 8 + sub;
    if (e >= ET) return;
    int s, d;
    if (e < E) { s = ei[e]; d = ei[E + e]; }
    else { s = e - E; d = s; }
    float alpha = e2[e] / s2[d];
    atomicAdd(&agg2[d * OUT_DIM + j], h2[s * OUT_DIM + j] * alpha);
}

// ---------------- final: bias + log_softmax ----------------
// block = 64 threads, grid = N
__global__ void k_logsoftmax(const float* __restrict__ agg2, const float* __restrict__ bias2,
                             float* __restrict__ out) {
    int n = blockIdx.x;
    int t = threadIdx.x;
    float v = (t < OUT_DIM) ? (agg2[n * OUT_DIM + t] + bias2[t]) : -INFINITY;
    float mx = v;
#pragma unroll
    for (int o = 32; o > 0; o >>= 1) mx = fmaxf(mx, __shfl_down(mx, o));
    mx = __shfl(mx, 0);
    float ex = (t < OUT_DIM) ? expf(v - mx) : 0.0f;
    float sm = ex;
#pragma unroll
    for (int o = 32; o > 0; o >>= 1) sm += __shfl_down(sm, o);
    sm = __shfl(sm, 0);
    if (t < OUT_DIM) out[n * OUT_DIM + t] = v - mx - logf(sm);
}

extern "C" void kernel_launch(void* const* d_in, const int* in_sizes, int n_in,
                              void* d_out, int out_size, void* d_ws, size_t ws_size,
                              hipStream_t stream) {
    const float* x        = (const float*)d_in[0];
    const int*   ei       = (const int*)d_in[1];   // [2, E] int32
    const float* W1       = (const float*)d_in[2];
    const float* att_src1 = (const float*)d_in[3];
    const float* att_dst1 = (const float*)d_in[4];
    const float* bias1    = (const float*)d_in[5];
    const float* W2       = (const float*)d_in[6];
    const float* att_src2 = (const float*)d_in[7];
    const float* att_dst2 = (const float*)d_in[8];
    const float* bias2    = (const float*)d_in[9];
    float* out = (float*)d_out;

    const int N  = in_sizes[0] / IN_DIM;   // 10000
    const int E  = in_sizes[1] / 2;        // 320000
    const int ET = E + N;                  // 330000 (self-loops appended)

    // workspace layout (floats)
    float* w = (float*)d_ws;
    size_t off = 0;
    float* h1   = w + off; off += (size_t)N * C1;       // 2.56M
    float* as1  = w + off; off += (size_t)N * H1;
    float* ad1  = w + off; off += (size_t)N * H1;
    float* m1   = w + off; off += (size_t)N * H1;
    float* s1   = w + off; off += (size_t)N * H1;
    float* e1   = w + off; off += (size_t)ET * H1;      // 1.32M
    float* agg1 = w + off; off += (size_t)N * C1;       // 2.56M
    float* h2   = w + off; off += (size_t)N * OUT_DIM;  // 0.4M
    float* as2  = w + off; off += (size_t)N;
    float* ad2  = w + off; off += (size_t)N;
    float* m2   = w + off; off += (size_t)N;
    float* s2   = w + off; off += (size_t)N;
    float* e2   = w + off; off += (size_t)ET;           // 0.33M
    float* agg2 = w + off; off += (size_t)N * OUT_DIM;  // 0.4M

    // 1. init
    {
        int tot = N * C1;
        k_init<<<(tot + 255) / 256, 256, 0, stream>>>(m1, s1, agg1, m2, s2, agg2, N);
    }
    // 2. layer-1 GEMM + attention dots
    k_gemm1<<<N, 256, 0, stream>>>(x, W1, att_src1, att_dst1, h1, as1, ad1);
    // 3. edge max
    k_edge_max1<<<(ET + 255) / 256, 256, 0, stream>>>(ei, E, ET, as1, ad1, e1, m1);
    // 4. edge exp + sum
    k_edge_exp1<<<(ET + 255) / 256, 256, 0, stream>>>(ei, E, ET, e1, m1, s1);
    // 5. aggregate
    k_agg1<<<ET, 256, 0, stream>>>(ei, E, ET, e1, s1, h1, agg1);
    // 6. layer-2 GEMM (with relu+bias fused on input)
    k_gemm2<<<N, 64, 0, stream>>>(agg1, bias1, W2, att_src2, att_dst2, h2, as2, ad2);
    // 7. edge max
    k_edge_max2<<<(ET + 255) / 256, 256, 0, stream>>>(ei, E, ET, as2, ad2, e2, m2);
    // 8. edge exp + sum
    k_edge_exp2<<<(ET + 255) / 256, 256, 0, stream>>>(ei, E, ET, e2, m2, s2);
    // 9. aggregate
    k_agg2<<<(ET + 7) / 8, 320, 0, stream>>>(ei, E, ET, e2, s2, h2, agg2);
    // 10. bias + log_softmax
    k_logsoftmax<<<N, 64, 0, stream>>>(agg2, bias2, out);
}

// Round 2
// 291.231 us; speedup vs baseline: 2.4124x; 2.4124x over previous
//
#include <hip/hip_runtime.h>
#include <hip/hip_bf16.h>
#include <math.h>

// N=10000, E=320000, in_dim=256, heads=4, hidden=64 (C1=256), out=40
#define IN_DIM 256
#define C1 256
#define H1 4
#define D1 64
#define OUT_DIM 40
#define NEG_SLOPE 0.2f
#define TM 8   // nodes per block in GEMMs

// ---------------- CSR build ----------------
__global__ void k_zero(int* deg, int N) {
    int i = blockIdx.x * blockDim.x + threadIdx.x;
    if (i < N) deg[i] = 0;
}

__global__ void k_hist(const int* __restrict__ ei, int E, int ET, int* __restrict__ deg) {
    int e = blockIdx.x * blockDim.x + threadIdx.x;
    if (e >= ET) return;
    int d = (e < E) ? ei[E + e] : (e - E);
    atomicAdd(&deg[d], 1);
}

// single block, 256 threads: exclusive scan of deg -> row_ptr, fill (copy)
__global__ void k_scan(const int* __restrict__ deg, int* __restrict__ row_ptr,
                       int* __restrict__ fill, int N) {
    __shared__ int part[256];
    int t = threadIdx.x;
    int per = (N + 255) / 256;
    int base = t * per;
    int sum = 0;
    for (int i = 0; i < per; ++i) {
        int idx = base + i;
        if (idx < N) sum += deg[idx];
    }
    part[t] = sum;
    __syncthreads();
    for (int off = 1; off < 256; off <<= 1) {
        int v = (t >= off) ? part[t - off] : 0;
        __syncthreads();
        part[t] += v;
        __syncthreads();
    }
    int run = (t == 0) ? 0 : part[t - 1];
    for (int i = 0; i < per; ++i) {
        int idx = base + i;
        if (idx < N) {
            row_ptr[idx] = run;
            fill[idx] = run;
            run += deg[idx];
        }
    }
    if (t == 255) row_ptr[N] = part[255];
}

__global__ void k_scatter(const int* __restrict__ ei, int E, int ET,
                          int* __restrict__ fill, int* __restrict__ srcs) {
    int e = blockIdx.x * blockDim.x + threadIdx.x;
    if (e >= ET) return;
    int s, d;
    if (e < E) { s = ei[e]; d = ei[E + e]; }
    else       { s = e - E; d = s; }
    int pos = atomicAdd(&fill[d], 1);
    srcs[pos] = s;
}

// ---------------- layer 1 GEMM (+attention dots), 8 nodes/block ----------------
__global__ void k_gemm1(const float* __restrict__ x, const float* __restrict__ W1,
                        const float* __restrict__ a_src, const float* __restrict__ a_dst,
                        float* __restrict__ h1, float* __restrict__ as1, float* __restrict__ ad1,
                        int N) {
    int n0 = blockIdx.x * TM;
    int t = threadIdx.x;
    __shared__ float xs[TM][IN_DIM];
#pragma unroll
    for (int m = 0; m < TM; ++m) {
        int n = n0 + m;
        xs[m][t] = (n < N) ? x[(size_t)n * IN_DIM + t] : 0.0f;
    }
    __syncthreads();
    float acc[TM];
#pragma unroll
    for (int m = 0; m < TM; ++m) acc[m] = 0.0f;
#pragma unroll 4
    for (int k = 0; k < IN_DIM; ++k) {
        float w = W1[k * C1 + t];
#pragma unroll
        for (int m = 0; m < TM; ++m) acc[m] += xs[m][k] * w;
    }
    float asv = a_src[t];
    float adv = a_dst[t];
    int head = t >> 6;
#pragma unroll
    for (int m = 0; m < TM; ++m) {
        int n = n0 + m;
        if (n < N) h1[(size_t)n * C1 + t] = acc[m];
        float ps = acc[m] * asv;
        float pd = acc[m] * adv;
#pragma unroll
        for (int o = 32; o > 0; o >>= 1) {
            ps += __shfl_down(ps, o);
            pd += __shfl_down(pd, o);
        }
        if ((t & 63) == 0 && n < N) {
            as1[n * H1 + head] = ps;
            ad1[n * H1 + head] = pd;
        }
    }
}

// ---------------- layer 1 fused softmax + aggregate (per dst node) ----------------
// grid = N, block = 256 (wave w == head w). Epilogue: +bias1, relu -> agg1r.
__global__ void k_node1(const int* __restrict__ row_ptr, const int* __restrict__ srcs,
                        const float* __restrict__ as1, const float* __restrict__ ad1,
                        const float* __restrict__ h1, const float* __restrict__ bias1,
                        float* __restrict__ e1s, float* __restrict__ agg1r, int ET) {
    int n = blockIdx.x;
    int t = threadIdx.x;
    int h = t >> 6;
    int lane = t & 63;
    int start = row_ptr[n];
    int end = row_ptr[n + 1];
    __shared__ float sM[H1], sS[H1];
    float adn = ad1[n * H1 + h];

    // pass A: compute raw scores, store, reduce max (per head == per wave)
    float mx = -INFINITY;
    for (int i = start + lane; i < end; i += 64) {
        int s = srcs[i];
        float v = as1[s * H1 + h] + adn;
        v = (v >= 0.0f) ? v : NEG_SLOPE * v;
        e1s[(size_t)h * ET + i] = v;
        mx = fmaxf(mx, v);
    }
#pragma unroll
    for (int o = 32; o > 0; o >>= 1) mx = fmaxf(mx, __shfl_xor(mx, o));
    if (lane == 0) sM[h] = mx;
    __syncthreads();
    float M = sM[h];

    // pass B: exp, store, reduce sum
    float sm = 0.0f;
    for (int i = start + lane; i < end; i += 64) {
        float ex = __expf(e1s[(size_t)h * ET + i] - M);
        e1s[(size_t)h * ET + i] = ex;
        sm += ex;
    }
#pragma unroll
    for (int o = 32; o > 0; o >>= 1) sm += __shfl_xor(sm, o);
    if (lane == 0) sS[h] = sm;
    __syncthreads();
    float invS = 1.0f / sS[h];

    // pass C: weighted gather-accumulate (registers), single write
    float acc = 0.0f;
    int i = start;
    for (; i + 1 < end; i += 2) {
        int s0 = srcs[i], s1 = srcs[i + 1];
        float a0 = e1s[(size_t)h * ET + i] * invS;
        float a1 = e1s[(size_t)h * ET + i + 1] * invS;
        acc += h1[(size_t)s0 * C1 + t] * a0 + h1[(size_t)s1 * C1 + t] * a1;
    }
    if (i < end) {
        int s0 = srcs[i];
        float a0 = e1s[(size_t)h * ET + i] * invS;
        acc += h1[(size_t)s0 * C1 + t] * a0;
    }
    float v = acc + bias1[t];
    agg1r[(size_t)n * C1 + t] = (v > 0.0f) ? v : 0.0f;  // fused bias+relu
}

// ---------------- layer 2 GEMM (+attention dots), 8 nodes/block, 64 threads ----------------
__global__ void k_gemm2(const float* __restrict__ agg1r, const float* __restrict__ W2,
                        const float* __restrict__ a_src, const float* __restrict__ a_dst,
                        float* __restrict__ h2, float* __restrict__ as2, float* __restrict__ ad2,
                        int N) {
    int n0 = blockIdx.x * TM;
    int t = threadIdx.x;  // 64
    __shared__ float xs[TM][C1];
#pragma unroll
    for (int m = 0; m < TM; ++m) {
        int n = n0 + m;
        for (int i = t; i < C1; i += 64)
            xs[m][i] = (n < N) ? agg1r[(size_t)n * C1 + i] : 0.0f;
    }
    __syncthreads();
    float acc[TM];
#pragma unroll
    for (int m = 0; m < TM; ++m) acc[m] = 0.0f;
    if (t < OUT_DIM) {
#pragma unroll 4
        for (int k = 0; k < C1; ++k) {
            float w = W2[k * OUT_DIM + t];
#pragma unroll
            for (int m = 0; m < TM; ++m) acc[m] += xs[m][k] * w;
        }
    }
    float asv = (t < OUT_DIM) ? a_src[t] : 0.0f;
    float adv = (t < OUT_DIM) ? a_dst[t] : 0.0f;
#pragma unroll
    for (int m = 0; m < TM; ++m) {
        int n = n0 + m;
        if (t < OUT_DIM && n < N) h2[(size_t)n * OUT_DIM + t] = acc[m];
        float ps = acc[m] * asv;
        float pd = acc[m] * adv;
#pragma unroll
        for (int o = 32; o > 0; o >>= 1) {
            ps += __shfl_down(ps, o);
            pd += __shfl_down(pd, o);
        }
        if (t == 0 && n < N) { as2[n] = ps; ad2[n] = pd; }
    }
}

// ---------------- layer 2 fused softmax + aggregate + bias + log_softmax ----------------
// grid = N, block = 64 (one wave)
__global__ void k_node2(const int* __restrict__ row_ptr, const int* __restrict__ srcs,
                        const float* __restrict__ as2, const float* __restrict__ ad2,
                        const float* __restrict__ h2, const float* __restrict__ bias2,
                        float* __restrict__ e2s, float* __restrict__ out) {
    int n = blockIdx.x;
    int t = threadIdx.x;
    int start = row_ptr[n];
    int end = row_ptr[n + 1];
    float adn = ad2[n];

    // pass A: raw scores + max
    float mx = -INFINITY;
    for (int i = start + t; i < end; i += 64) {
        int s = srcs[i];
        float v = as2[s] + adn;
        v = (v >= 0.0f) ? v : NEG_SLOPE * v;
        e2s[i] = v;
        mx = fmaxf(mx, v);
    }
#pragma unroll
    for (int o = 32; o > 0; o >>= 1) mx = fmaxf(mx, __shfl_xor(mx, o));
    // pass B: exp + sum
    float sm = 0.0f;
    for (int i = start + t; i < end; i += 64) {
        float ex = __expf(e2s[i] - mx);
        e2s[i] = ex;
        sm += ex;
    }
#pragma unroll
    for (int o = 32; o > 0; o >>= 1) sm += __shfl_xor(sm, o);
    float invS = 1.0f / sm;
    __syncthreads();

    // pass C: weighted gather-accumulate (t < OUT_DIM lanes active)
    float acc = 0.0f;
    for (int i = start; i < end; ++i) {
        int s = srcs[i];
        float a = e2s[i] * invS;
        if (t < OUT_DIM) acc += h2[(size_t)s * OUT_DIM + t] * a;
    }
    // fused +bias2 and log_softmax over the 40 outputs
    float val = (t < OUT_DIM) ? (acc + bias2[t]) : -INFINITY;
    float vmx = val;
#pragma unroll
    for (int o = 32; o > 0; o >>= 1) vmx = fmaxf(vmx, __shfl_xor(vmx, o));
    float ex = (t < OUT_DIM) ? __expf(val - vmx) : 0.0f;
    float es = ex;
#pragma unroll
    for (int o = 32; o > 0; o >>= 1) es += __shfl_xor(es, o);
    if (t < OUT_DIM) out[(size_t)n * OUT_DIM + t] = val - vmx - logf(es);
}

extern "C" void kernel_launch(void* const* d_in, const int* in_sizes, int n_in,
                              void* d_out, int out_size, void* d_ws, size_t ws_size,
                              hipStream_t stream) {
    const float* x        = (const float*)d_in[0];
    const int*   ei       = (const int*)d_in[1];
    const float* W1       = (const float*)d_in[2];
    const float* att_src1 = (const float*)d_in[3];
    const float* att_dst1 = (const float*)d_in[4];
    const float* bias1    = (const float*)d_in[5];
    const float* W2       = (const float*)d_in[6];
    const float* att_src2 = (const float*)d_in[7];
    const float* att_dst2 = (const float*)d_in[8];
    const float* bias2    = (const float*)d_in[9];
    float* out = (float*)d_out;

    const int N  = in_sizes[0] / IN_DIM;   // 10000
    const int E  = in_sizes[1] / 2;        // 320000
    const int ET = E + N;                  // 330000

    // workspace layout
    float* w = (float*)d_ws;
    size_t off = 0;
    float* h1    = w + off; off += (size_t)N * C1;        // 2.56M
    float* agg1r = w + off; off += (size_t)N * C1;        // 2.56M
    float* as1   = w + off; off += (size_t)N * H1;
    float* ad1   = w + off; off += (size_t)N * H1;
    float* e1s   = w + off; off += (size_t)ET * H1;       // 1.32M
    float* h2    = w + off; off += (size_t)N * OUT_DIM;   // 0.4M
    float* as2   = w + off; off += (size_t)N;
    float* ad2   = w + off; off += (size_t)N;
    float* e2s   = w + off; off += (size_t)ET;            // 0.33M
    int* ib      = (int*)(w + off);
    size_t ioff = 0;
    int* deg     = ib + ioff; ioff += N;
    int* row_ptr = ib + ioff; ioff += N + 1;
    int* fill    = ib + ioff; ioff += N;
    int* srcs    = ib + ioff; ioff += ET;

    // CSR build
    k_zero<<<(N + 255) / 256, 256, 0, stream>>>(deg, N);
    k_hist<<<(ET + 255) / 256, 256, 0, stream>>>(ei, E, ET, deg);
    k_scan<<<1, 256, 0, stream>>>(deg, row_ptr, fill, N);
    k_scatter<<<(ET + 255) / 256, 256, 0, stream>>>(ei, E, ET, fill, srcs);

    // layer 1
    k_gemm1<<<(N + TM - 1) / TM, 256, 0, stream>>>(x, W1, att_src1, att_dst1, h1, as1, ad1, N);
    k_node1<<<N, 256, 0, stream>>>(row_ptr, srcs, as1, ad1, h1, bias1, e1s, agg1r, ET);

    // layer 2
    k_gemm2<<<(N + TM - 1) / TM, 64, 0, stream>>>(agg1r, W2, att_src2, att_dst2, h2, as2, ad2, N);
    k_node2<<<N, 64, 0, stream>>>(row_ptr, srcs, as2, ad2, h2, bias2, e2s, out);
}

// Round 3
// 270.810 us; speedup vs baseline: 2.5943x; 1.0754x over previous
//
#include <hip/hip_runtime.h>
#include <hip/hip_bf16.h>
#include <math.h>

// N=10000, E=320000, in_dim=256, heads=4, hidden=64 (C1=256), out=40
#define IN_DIM 256
#define C1 256
#define H1 4
#define OUT_DIM 40
#define NEG_SLOPE 0.2f
#define TM 8   // nodes per block in gemm1

__device__ __forceinline__ unsigned short f2bf(float f) {
    union { float f; unsigned u; } c; c.f = f;
    unsigned r = c.u + 0x7fffu + ((c.u >> 16) & 1u);
    return (unsigned short)(r >> 16);
}

__device__ __forceinline__ float sel4(float4 v, int h) {
    float r = v.x;
    r = (h == 1) ? v.y : r;
    r = (h == 2) ? v.z : r;
    r = (h == 3) ? v.w : r;
    return r;
}

__device__ __forceinline__ float leaky(float v) {
    return (v >= 0.0f) ? v : NEG_SLOPE * v;
}

// ---------------- prep: zero deg + precompute W2@a_src2, W2@a_dst2 ----------------
__global__ void k_prep(int* __restrict__ deg, const float* __restrict__ W2,
                       const float* __restrict__ a_src2, const float* __restrict__ a_dst2,
                       float* __restrict__ w2s, float* __restrict__ w2d, int N) {
    int g = blockIdx.x * blockDim.x + threadIdx.x;
    if (g < N) deg[g] = 0;
    if (g < C1) {
        float s = 0.0f, d = 0.0f;
#pragma unroll
        for (int j = 0; j < OUT_DIM; ++j) {
            float w = W2[g * OUT_DIM + j];
            s += w * a_src2[j];
            d += w * a_dst2[j];
        }
        w2s[g] = s;
        w2d[g] = d;
    }
}

__global__ void k_hist(const int* __restrict__ ei, int E, int ET, int* __restrict__ deg) {
    int e = blockIdx.x * blockDim.x + threadIdx.x;
    if (e >= ET) return;
    int d = (e < E) ? ei[E + e] : (e - E);
    atomicAdd(&deg[d], 1);
}

// single block, 1024 threads: exclusive scan deg -> row_ptr, fill
__global__ void k_scan(const int* __restrict__ deg, int* __restrict__ row_ptr,
                       int* __restrict__ fill, int N) {
    __shared__ int part[1024];
    int t = threadIdx.x;
    int per = (N + 1023) / 1024;
    int base = t * per;
    int sum = 0;
    for (int i = 0; i < per; ++i) {
        int idx = base + i;
        if (idx < N) sum += deg[idx];
    }
    part[t] = sum;
    __syncthreads();
    for (int off = 1; off < 1024; off <<= 1) {
        int v = (t >= off) ? part[t - off] : 0;
        __syncthreads();
        part[t] += v;
        __syncthreads();
    }
    int run = (t == 0) ? 0 : part[t - 1];
    for (int i = 0; i < per; ++i) {
        int idx = base + i;
        if (idx < N) {
            row_ptr[idx] = run;
            fill[idx] = run;
            run += deg[idx];
        }
    }
    if (t == 1023) row_ptr[N] = part[1023];
}

__global__ void k_scatter(const int* __restrict__ ei, int E, int ET,
                          int* __restrict__ fill, int* __restrict__ srcs) {
    int e = blockIdx.x * blockDim.x + threadIdx.x;
    if (e >= ET) return;
    int s, d;
    if (e < E) { s = ei[e]; d = ei[E + e]; }
    else       { s = e - E; d = s; }
    int pos = atomicAdd(&fill[d], 1);
    srcs[pos] = s;
}

// ---------------- layer 1 GEMM (+attention dots), 8 nodes/block ----------------
__global__ void k_gemm1(const float* __restrict__ x, const float* __restrict__ W1,
                        const float* __restrict__ a_src, const float* __restrict__ a_dst,
                        unsigned short* __restrict__ h1, float* __restrict__ as1,
                        float* __restrict__ ad1, int N) {
    int n0 = blockIdx.x * TM;
    int t = threadIdx.x;
    __shared__ float xs[TM][IN_DIM];
#pragma unroll
    for (int m = 0; m < TM; ++m) {
        int n = n0 + m;
        xs[m][t] = (n < N) ? x[(size_t)n * IN_DIM + t] : 0.0f;
    }
    __syncthreads();
    float acc[TM];
#pragma unroll
    for (int m = 0; m < TM; ++m) acc[m] = 0.0f;
#pragma unroll 4
    for (int k = 0; k < IN_DIM; ++k) {
        float w = W1[k * C1 + t];
#pragma unroll
        for (int m = 0; m < TM; ++m) acc[m] += xs[m][k] * w;
    }
    float asv = a_src[t];
    float adv = a_dst[t];
    int head = t >> 6;
#pragma unroll
    for (int m = 0; m < TM; ++m) {
        int n = n0 + m;
        if (n < N) h1[(size_t)n * C1 + t] = f2bf(acc[m]);
        float ps = acc[m] * asv;
        float pd = acc[m] * adv;
#pragma unroll
        for (int o = 32; o > 0; o >>= 1) {
            ps += __shfl_down(ps, o);
            pd += __shfl_down(pd, o);
        }
        if ((t & 63) == 0 && n < N) {
            as1[n * H1 + head] = ps;
            ad1[n * H1 + head] = pd;
        }
    }
}

// ---------------- layer 1 fused softmax + aggregate, one wave per node ----------------
// lane handles dims [4*lane, 4*lane+4); head = lane>>4
// epilogue: +bias1, relu -> agg1r; dot with w2s/w2d -> as2/ad2 (layer-2 scores)
__global__ void k_node1(const int* __restrict__ row_ptr, const int* __restrict__ srcs,
                        const float* __restrict__ as1f, const float* __restrict__ ad1f,
                        const unsigned short* __restrict__ h1, const float* __restrict__ bias1,
                        const float* __restrict__ w2s, const float* __restrict__ w2d,
                        float* __restrict__ agg1r, float* __restrict__ as2,
                        float* __restrict__ ad2) {
    int n = blockIdx.x;
    int lane = threadIdx.x;  // 64
    int start = row_ptr[n], end = row_ptr[n + 1];
    const float4* as4 = (const float4*)as1f;
    float4 adn = ((const float4*)ad1f)[n];

    // pass A: per-head max over edges
    float4 mx = make_float4(-INFINITY, -INFINITY, -INFINITY, -INFINITY);
    for (int i = start + lane; i < end; i += 64) {
        int s = srcs[i];
        float4 a = as4[s];
        mx.x = fmaxf(mx.x, leaky(a.x + adn.x));
        mx.y = fmaxf(mx.y, leaky(a.y + adn.y));
        mx.z = fmaxf(mx.z, leaky(a.z + adn.z));
        mx.w = fmaxf(mx.w, leaky(a.w + adn.w));
    }
#pragma unroll
    for (int o = 32; o > 0; o >>= 1) {
        mx.x = fmaxf(mx.x, __shfl_xor(mx.x, o));
        mx.y = fmaxf(mx.y, __shfl_xor(mx.y, o));
        mx.z = fmaxf(mx.z, __shfl_xor(mx.z, o));
        mx.w = fmaxf(mx.w, __shfl_xor(mx.w, o));
    }
    // pass B: per-head sum of exp
    float4 sm = make_float4(0.f, 0.f, 0.f, 0.f);
    for (int i = start + lane; i < end; i += 64) {
        int s = srcs[i];
        float4 a = as4[s];
        sm.x += __expf(leaky(a.x + adn.x) - mx.x);
        sm.y += __expf(leaky(a.y + adn.y) - mx.y);
        sm.z += __expf(leaky(a.z + adn.z) - mx.z);
        sm.w += __expf(leaky(a.w + adn.w) - mx.w);
    }
#pragma unroll
    for (int o = 32; o > 0; o >>= 1) {
        sm.x += __shfl_xor(sm.x, o);
        sm.y += __shfl_xor(sm.y, o);
        sm.z += __shfl_xor(sm.z, o);
        sm.w += __shfl_xor(sm.w, o);
    }
    int h = lane >> 4;
    float Mh   = sel4(mx, h);
    float iSh  = 1.0f / sel4(sm, h);
    float adnh = sel4(adn, h);

    // pass C: weighted gather-accumulate, 4 dims per lane (bf16x4 = 8B loads)
    float ac0 = 0.f, ac1 = 0.f, ac2 = 0.f, ac3 = 0.f;
    for (int i = start; i < end; ++i) {
        int s = srcs[i];  // wave-uniform
        float sc = leaky(as1f[s * H1 + h] + adnh);
        float alpha = __expf(sc - Mh) * iSh;
        uint2 raw = ((const uint2*)(h1 + (size_t)s * C1))[lane];
        ac0 += alpha * __uint_as_float(raw.x << 16);
        ac1 += alpha * __uint_as_float(raw.x & 0xffff0000u);
        ac2 += alpha * __uint_as_float(raw.y << 16);
        ac3 += alpha * __uint_as_float(raw.y & 0xffff0000u);
    }
    float4 b = ((const float4*)bias1)[lane];
    float v0 = fmaxf(ac0 + b.x, 0.f);
    float v1 = fmaxf(ac1 + b.y, 0.f);
    float v2 = fmaxf(ac2 + b.z, 0.f);
    float v3 = fmaxf(ac3 + b.w, 0.f);
    ((float4*)agg1r)[(size_t)n * (C1 / 4) + lane] = make_float4(v0, v1, v2, v3);

    // layer-2 attention dots: as2[n] = relu_row . (W2 @ a_src2), same for ad2
    float4 ws = ((const float4*)w2s)[lane];
    float4 wd = ((const float4*)w2d)[lane];
    float ps = v0 * ws.x + v1 * ws.y + v2 * ws.z + v3 * ws.w;
    float pd = v0 * wd.x + v1 * wd.y + v2 * wd.z + v3 * wd.w;
#pragma unroll
    for (int o = 32; o > 0; o >>= 1) {
        ps += __shfl_xor(ps, o);
        pd += __shfl_xor(pd, o);
    }
    if (lane == 0) { as2[n] = ps; ad2[n] = pd; }
}

// ---------------- layer 2 GEMM: h2 = agg1r @ W2, 4 nodes x 64 lanes ----------------
__global__ void k_gemm2(const float* __restrict__ agg1r, const float* __restrict__ W2,
                        float* __restrict__ h2, int N) {
    int t = threadIdx.x;  // 256
    int m = t >> 6;
    int j = t & 63;
    int n = blockIdx.x * 4 + m;
    __shared__ float xs[4][C1];
    for (int i = t; i < 4 * C1; i += 256) {
        int mm = i >> 8;
        int nn = blockIdx.x * 4 + mm;
        xs[mm][i & (C1 - 1)] = (nn < N) ? agg1r[(size_t)nn * C1 + (i & (C1 - 1))] : 0.0f;
    }
    __syncthreads();
    if (j < OUT_DIM && n < N) {
        float acc = 0.0f;
#pragma unroll 4
        for (int k = 0; k < C1; ++k) acc += xs[m][k] * W2[k * OUT_DIM + j];
        h2[(size_t)n * OUT_DIM + j] = acc;
    }
}

// ---------------- layer 2 fused softmax + aggregate + bias + log_softmax ----------------
// grid = N, block = 256 (4 waves)
__global__ void k_node2(const int* __restrict__ row_ptr, const int* __restrict__ srcs,
                        const float* __restrict__ as2, const float* __restrict__ ad2,
                        const float* __restrict__ h2, const float* __restrict__ bias2,
                        float* __restrict__ out) {
    int n = blockIdx.x;
    int t = threadIdx.x;
    int wv = t >> 6;
    int lane = t & 63;
    int start = row_ptr[n], end = row_ptr[n + 1];
    float adn = ad2[n];
    __shared__ float red[4];
    __shared__ float accs[4][OUT_DIM];

    // pass A: max
    float mx = -INFINITY;
    for (int i = start + t; i < end; i += 256)
        mx = fmaxf(mx, leaky(as2[srcs[i]] + adn));
#pragma unroll
    for (int o = 32; o > 0; o >>= 1) mx = fmaxf(mx, __shfl_xor(mx, o));
    if (lane == 0) red[wv] = mx;
    __syncthreads();
    mx = fmaxf(fmaxf(red[0], red[1]), fmaxf(red[2], red[3]));
    __syncthreads();

    // pass B: sum of exp
    float sm = 0.0f;
    for (int i = start + t; i < end; i += 256)
        sm += __expf(leaky(as2[srcs[i]] + adn) - mx);
#pragma unroll
    for (int o = 32; o > 0; o >>= 1) sm += __shfl_xor(sm, o);
    if (lane == 0) red[wv] = sm;
    __syncthreads();
    float invS = 1.0f / (red[0] + red[1] + red[2] + red[3]);

    // pass C: each wave handles every 4th edge; lanes<40 hold output dims
    float acc = 0.0f;
    for (int i = start + wv; i < end; i += 4) {
        int s = srcs[i];  // wave-uniform
        float alpha = __expf(leaky(as2[s] + adn) - mx) * invS;
        if (lane < OUT_DIM) acc += h2[(size_t)s * OUT_DIM + lane] * alpha;
    }
    if (lane < OUT_DIM) accs[wv][lane] = acc;
    __syncthreads();

    if (t < 64) {
        float val = -INFINITY;
        if (t < OUT_DIM)
            val = accs[0][t] + accs[1][t] + accs[2][t] + accs[3][t] + bias2[t];
        float vmx = val;
#pragma unroll
        for (int o = 32; o > 0; o >>= 1) vmx = fmaxf(vmx, __shfl_xor(vmx, o));
        float ex = (t < OUT_DIM) ? __expf(val - vmx) : 0.0f;
        float es = ex;
#pragma unroll
        for (int o = 32; o > 0; o >>= 1) es += __shfl_xor(es, o);
        if (t < OUT_DIM) out[(size_t)n * OUT_DIM + t] = val - vmx - logf(es);
    }
}

extern "C" void kernel_launch(void* const* d_in, const int* in_sizes, int n_in,
                              void* d_out, int out_size, void* d_ws, size_t ws_size,
                              hipStream_t stream) {
    const float* x        = (const float*)d_in[0];
    const int*   ei       = (const int*)d_in[1];
    const float* W1       = (const float*)d_in[2];
    const float* att_src1 = (const float*)d_in[3];
    const float* att_dst1 = (const float*)d_in[4];
    const float* bias1    = (const float*)d_in[5];
    const float* W2       = (const float*)d_in[6];
    const float* att_src2 = (const float*)d_in[7];
    const float* att_dst2 = (const float*)d_in[8];
    const float* bias2    = (const float*)d_in[9];
    float* out = (float*)d_out;

    const int N  = in_sizes[0] / IN_DIM;   // 10000
    const int E  = in_sizes[1] / 2;        // 320000
    const int ET = E + N;                  // 330000

    // workspace layout (256B-aligned chunks)
    char* base = (char*)d_ws;
    auto alloc = [&](size_t bytes) {
        char* p = base;
        base += (bytes + 255) & ~(size_t)255;
        return p;
    };
    unsigned short* h1 = (unsigned short*)alloc((size_t)N * C1 * 2);
    float* agg1r = (float*)alloc((size_t)N * C1 * 4);
    float* as1   = (float*)alloc((size_t)N * H1 * 4);
    float* ad1   = (float*)alloc((size_t)N * H1 * 4);
    float* h2    = (float*)alloc((size_t)N * OUT_DIM * 4);
    float* as2   = (float*)alloc((size_t)N * 4);
    float* ad2   = (float*)alloc((size_t)N * 4);
    float* w2s   = (float*)alloc((size_t)C1 * 4);
    float* w2d   = (float*)alloc((size_t)C1 * 4);
    int* deg     = (int*)alloc((size_t)N * 4);
    int* row_ptr = (int*)alloc((size_t)(N + 1) * 4);
    int* fill    = (int*)alloc((size_t)N * 4);
    int* srcs    = (int*)alloc((size_t)ET * 4);

    // CSR build + prep
    k_prep<<<(N + 255) / 256, 256, 0, stream>>>(deg, W2, att_src2, att_dst2, w2s, w2d, N);
    k_hist<<<(ET + 255) / 256, 256, 0, stream>>>(ei, E, ET, deg);
    k_scan<<<1, 1024, 0, stream>>>(deg, row_ptr, fill, N);
    k_scatter<<<(ET + 255) / 256, 256, 0, stream>>>(ei, E, ET, fill, srcs);

    // layer 1
    k_gemm1<<<(N + TM - 1) / TM, 256, 0, stream>>>(x, W1, att_src1, att_dst1, h1, as1, ad1, N);
    k_node1<<<N, 64, 0, stream>>>(row_ptr, srcs, as1, ad1, h1, bias1, w2s, w2d, agg1r, as2, ad2);

    // layer 2
    k_gemm2<<<(N + 3) / 4, 256, 0, stream>>>(agg1r, W2, h2, N);
    k_node2<<<N, 256, 0, stream>>>(row_ptr, srcs, as2, ad2, h2, bias2, out);
}